// Round 2
// baseline (218.708 us; speedup 1.0000x reference)
//
#include <hip/hip_runtime.h>

#define BLOCK 256
#define GRID 2048

__device__ __forceinline__ float gmgs_term(float pv, float tv, const float* __restrict__ sm_e) {
    // class = clip(floor(x), -1, 2) + 1  ->  {0,1,2,3}
    float pf = fminf(fmaxf(floorf(pv), -1.0f), 2.0f);
    float tf = fminf(fmaxf(floorf(tv), -1.0f), 2.0f);
    int pc = (int)pf + 1;
    int tc = (int)tf + 1;
    float d = pv - tv;
    return d * d * sm_e[tc * 4 + pc];
}

__device__ __forceinline__ float gmgs_quad(float4 p, float4 t, const float* __restrict__ sm_e) {
    return (gmgs_term(p.x, t.x, sm_e) + gmgs_term(p.y, t.y, sm_e))
         + (gmgs_term(p.z, t.z, sm_e) + gmgs_term(p.w, t.w, sm_e));
}

__global__ __launch_bounds__(BLOCK) void gmgs_loss_kernel(
    const float* __restrict__ pred,
    const float* __restrict__ tru,
    const float* __restrict__ score,
    float* __restrict__ out,
    int n4, int rem, float invB)
{
    __shared__ float sm_e[16];          // unnormalized exp(-score)
    __shared__ float sred[BLOCK / 64];

    const int tid = threadIdx.x;
    if (tid < 16) sm_e[tid] = expf(-score[tid]);
    __syncthreads();

    const float4* __restrict__ pred4 = (const float4*)pred;
    const float4* __restrict__ tru4  = (const float4*)tru;

    const int stride = GRID * BLOCK;
    int i = (int)blockIdx.x * BLOCK + tid;
    float acc0 = 0.0f, acc1 = 0.0f, acc2 = 0.0f, acc3 = 0.0f;

    // 4x unrolled grid-stride: 8 independent coalesced float4 loads in flight
    for (; i + 3 * stride < n4; i += 4 * stride) {
        float4 p0 = pred4[i];
        float4 p1 = pred4[i + stride];
        float4 p2 = pred4[i + 2 * stride];
        float4 p3 = pred4[i + 3 * stride];
        float4 t0 = tru4[i];
        float4 t1 = tru4[i + stride];
        float4 t2 = tru4[i + 2 * stride];
        float4 t3 = tru4[i + 3 * stride];
        acc0 += gmgs_quad(p0, t0, sm_e);
        acc1 += gmgs_quad(p1, t1, sm_e);
        acc2 += gmgs_quad(p2, t2, sm_e);
        acc3 += gmgs_quad(p3, t3, sm_e);
    }
    for (; i < n4; i += stride)
        acc0 += gmgs_quad(pred4[i], tru4[i], sm_e);

    // scalar tail (n % 4), handled by block 0
    if (blockIdx.x == 0 && tid < rem) {
        int j = n4 * 4 + tid;
        acc0 += gmgs_term(pred[j], tru[j], sm_e);
    }

    float acc = (acc0 + acc1) + (acc2 + acc3);
    #pragma unroll
    for (int off = 32; off > 0; off >>= 1)
        acc += __shfl_down(acc, off, 64);

    if ((tid & 63) == 0) sred[tid >> 6] = acc;
    __syncthreads();
    if (tid == 0) {
        float s = 0.0f;
        #pragma unroll
        for (int w = 0; w < BLOCK / 64; ++w) s += sred[w];
        float e = 0.0f;
        #pragma unroll
        for (int k = 0; k < 16; ++k) e += sm_e[k];
        // one device-scope atomic per block; out zeroed by memset in kernel_launch
        atomicAdd(out, s * invB / e);
    }
}

extern "C" void kernel_launch(void* const* d_in, const int* in_sizes, int n_in,
                              void* d_out, int out_size, void* d_ws, size_t ws_size,
                              hipStream_t stream) {
    const float* pred  = (const float*)d_in[0];
    const float* tru   = (const float*)d_in[1];
    const float* score = (const float*)d_in[2];
    float* out = (float*)d_out;

    long long n = (long long)in_sizes[0];   // B*T*1
    int n4  = (int)(n >> 2);
    int rem = (int)(n & 3);
    long long B = n / 48;                   // T = 48 per problem setup
    float invB = 1.0f / (float)B;

    hipMemsetAsync(d_out, 0, sizeof(float), stream);
    gmgs_loss_kernel<<<GRID, BLOCK, 0, stream>>>(pred, tru, score, out, n4, rem, invB);
}

// Round 3
// 216.353 us; speedup vs baseline: 1.0109x; 1.0109x over previous
//
#include <hip/hip_runtime.h>

#define S1_BLOCK 256
#define S2_BLOCK 1024

__device__ __forceinline__ float gmgs_term(float pv, float tv, const float* __restrict__ sm_e) {
    // class = clip(floor(x), -1, 2) + 1  ->  {0,1,2,3}
    int pc = (int)fminf(fmaxf(floorf(pv), -1.0f), 2.0f) + 1;
    int tc = (int)fminf(fmaxf(floorf(tv), -1.0f), 2.0f) + 1;
    float d = pv - tv;
    return d * d * sm_e[(tc << 2) | pc];
}

// Stage 1: one float4-pair per thread, no loop -> block churn keeps the
// memory pipeline full (copy-ubench shape). Unnormalized partial per block.
__global__ __launch_bounds__(S1_BLOCK) void gmgs_stage1(
    const float4* __restrict__ pred4,
    const float4* __restrict__ tru4,
    const float* __restrict__ pred,
    const float* __restrict__ tru,
    const float* __restrict__ score,
    float* __restrict__ partials,
    int n4, int rem)
{
    __shared__ float sm_e[16];
    __shared__ float sred[S1_BLOCK / 64];

    const int tid = threadIdx.x;
    if (tid < 16) sm_e[tid] = expf(-score[tid]);
    __syncthreads();

    const int i = (int)blockIdx.x * S1_BLOCK + tid;
    float acc = 0.0f;
    if (i < n4) {
        float4 p = pred4[i];
        float4 t = tru4[i];
        acc = (gmgs_term(p.x, t.x, sm_e) + gmgs_term(p.y, t.y, sm_e))
            + (gmgs_term(p.z, t.z, sm_e) + gmgs_term(p.w, t.w, sm_e));
    }
    // scalar tail (n % 4) folded into block 0
    if (blockIdx.x == 0 && tid < rem) {
        int j = n4 * 4 + tid;
        acc += gmgs_term(pred[j], tru[j], sm_e);
    }

    #pragma unroll
    for (int off = 32; off > 0; off >>= 1)
        acc += __shfl_down(acc, off, 64);

    if ((tid & 63) == 0) sred[tid >> 6] = acc;
    __syncthreads();
    if (tid == 0) {
        float s = 0.0f;
        #pragma unroll
        for (int w = 0; w < S1_BLOCK / 64; ++w) s += sred[w];
        partials[blockIdx.x] = s;   // unnormalized
    }
}

// Stage 2: single block reduces all partials, applies 1/Z and 1/B.
__global__ __launch_bounds__(S2_BLOCK) void gmgs_stage2(
    const float* __restrict__ partials,
    const float* __restrict__ score,
    float* __restrict__ out,
    int nblk, float invB)
{
    __shared__ float sred[S2_BLOCK / 64];
    const int tid = threadIdx.x;

    float acc = 0.0f;
    for (int i = tid; i < nblk; i += S2_BLOCK) acc += partials[i];

    #pragma unroll
    for (int off = 32; off > 0; off >>= 1)
        acc += __shfl_down(acc, off, 64);

    if ((tid & 63) == 0) sred[tid >> 6] = acc;
    __syncthreads();
    if (tid == 0) {
        float s = 0.0f;
        #pragma unroll
        for (int w = 0; w < S2_BLOCK / 64; ++w) s += sred[w];
        float z = 0.0f;
        #pragma unroll
        for (int k = 0; k < 16; ++k) z += expf(-score[k]);
        out[0] = s * invB / z;
    }
}

extern "C" void kernel_launch(void* const* d_in, const int* in_sizes, int n_in,
                              void* d_out, int out_size, void* d_ws, size_t ws_size,
                              hipStream_t stream) {
    const float* pred  = (const float*)d_in[0];
    const float* tru   = (const float*)d_in[1];
    const float* score = (const float*)d_in[2];
    float* out = (float*)d_out;
    float* partials = (float*)d_ws;

    long long n = (long long)in_sizes[0];   // B*T*1
    int n4  = (int)(n >> 2);
    int rem = (int)(n & 3);
    long long B = n / 48;                   // T = 48 per problem setup
    float invB = 1.0f / (float)B;

    int nblk = (n4 + S1_BLOCK - 1) / S1_BLOCK;   // 24576 for this shape (96 KB of ws)

    gmgs_stage1<<<nblk, S1_BLOCK, 0, stream>>>(
        (const float4*)pred, (const float4*)tru, pred, tru, score, partials, n4, rem);
    gmgs_stage2<<<1, S2_BLOCK, 0, stream>>>(partials, score, out, nblk, invB);
}